// Round 6
// baseline (883.985 us; speedup 1.0000x reference)
//
#include <hip/hip_runtime.h>
#include <float.h>

// Problem constants (from reference file)
constexpr int C     = 512;          // DIM_CODES
constexpr int K     = 512;          // DICT_SIZE
constexpr int E     = 16;           // EMBED_DIM
constexpr int B     = 512;          // BATCH
constexpr int RPBLK = 128;          // batch rows per block
constexpr int MUS   = C * E;        // 8192, mu row stride

typedef __attribute__((ext_vector_type(8))) short short8;   // 8 bf16 = 4 VGPR
typedef __attribute__((ext_vector_type(4))) float floatx4;  // MFMA acc

// ---- verified numeric helpers (identical op order to rounds 4/5, absmax 0)
__device__ __forceinline__ float fdot4(const float4 a, const float4 b, float acc) {
    acc = fmaf(a.x, b.x, acc);
    acc = fmaf(a.y, b.y, acc);
    acc = fmaf(a.z, b.z, acc);
    acc = fmaf(a.w, b.w, acc);
    return acc;
}
__device__ __forceinline__ double ddot4(const float4 a, const float4 b, double acc) {
    return acc + ((double)a.x * b.x + (double)a.y * b.y
                + (double)a.z * b.z + (double)a.w * b.w);
}
__device__ __forceinline__ double dnrm4(const float4 a, double acc) {
    return acc + ((double)a.x * a.x + (double)a.y * a.y
                + (double)a.z * a.z + (double)a.w * a.w);
}
// bf16 round-to-nearest-even split
__device__ __forceinline__ unsigned short bf16_rtne(float x) {
    unsigned u = __float_as_uint(x);
    return (unsigned short)((u + 0x7FFFu + ((u >> 16) & 1u)) >> 16);
}
__device__ __forceinline__ float bf16f(unsigned short h) {
    return __uint_as_float((unsigned)h << 16);
}

// Block = (c, 128 rows); 4 waves; wave w owns row-tiles {w, w+4} (32 rows).
// dist(b,k) = ||d_k||^2 - 2 mu_b.d_k via mfma_f32_16x16x32_bf16 with a
// bf16x2 split: acc = A[mh|mh]*B[dh|dl] + A[ml|ml]*B[dh|dl] = full
// (mh+ml).(dh+dl). Per-lane running argmin per C-row; final 4-step
// intra-16-lane reduction. Rows with MFMA gap < 3e-3 fall back to the
// VERIFIED round-4/5 fp32 function (-> fp64 at 2.5e-4), so near-ties are
// decided by exactly the machinery that has produced absmax 0 all session.
__launch_bounds__(256, 4)
__global__ void vq_kernel(const float* __restrict__ mu,
                          const float* __restrict__ dict,
                          float* __restrict__ z,
                          float* __restrict__ zq,
                          float* __restrict__ oh)
{
    const int c    = blockIdx.x;
    const int b0   = blockIdx.y * RPBLK;
    const int tid  = threadIdx.x;
    const int lane = tid & 63;
    const int w    = tid >> 6;

    __shared__ short8 sA1[8 * 64];   // [rt][lane] mu-hi frag [mh|mh], 8 KB
    __shared__ short8 sA2[8 * 64];   // mu-lo frag [ml|ml],            8 KB
    __shared__ short8 sB [32 * 64];  // [ct][lane] code frag [dh|dl], 32 KB
    __shared__ float  snd[K];        // per-code ||d||^2 (fp32 chain),  2 KB
    __shared__ float  rbest[RPBLK];
    __shared__ float  rsec [RPBLK];
    __shared__ int    rbk  [RPBLK];

    const float* __restrict__ dbase = dict + (size_t)c * K * E;

    // ---- A staging: pos = rt*64+lane; lane layout for mfma 16x16x32 A:
    //      m = lane&15, k = (lane>>4)*8 + j. [mh|mh]: e = (quad&1)*8 + j.
#pragma unroll
    for (int rep = 0; rep < 2; ++rep) {
        const int pos = tid + rep * 256;
        const int rt = pos >> 6, ln = pos & 63;
        const int m = ln & 15, q = ln >> 4;
        const float* src = mu + (size_t)(b0 + rt * 16 + m) * MUS + c * E + (q & 1) * 8;
        short8 vh, vl;
#pragma unroll
        for (int j = 0; j < 8; ++j) {
            const float x = src[j];
            const unsigned short h = bf16_rtne(x);
            vh[j] = (short)h;
            vl[j] = (short)bf16_rtne(x - bf16f(h));
        }
        sA1[pos] = vh;
        sA2[pos] = vl;
    }

    // ---- B staging: pos = ct*64+lane; B layout: n = lane&15,
    //      k = (lane>>4)*8 + j. [dh(k<16) | dl(k>=16)]: part = quad>>1.
#pragma unroll
    for (int rep = 0; rep < 8; ++rep) {
        const int pos = tid + rep * 256;
        const int ct = pos >> 6, ln = pos & 63;
        const int n = ln & 15, q = ln >> 4;
        const int part = q >> 1;
        const float* src = dbase + (size_t)(ct * 16 + n) * E + (q & 1) * 8;
        short8 v;
#pragma unroll
        for (int j = 0; j < 8; ++j) {
            const float x = src[j];
            const unsigned short h = bf16_rtne(x);
            v[j] = part ? (short)bf16_rtne(x - bf16f(h)) : (short)h;
        }
        sB[pos] = v;
    }

    // ---- per-code norms, verified fp32 chain
#pragma unroll
    for (int rep = 0; rep < 2; ++rep) {
        const int k = tid + rep * 256;
        const float4* p = reinterpret_cast<const float4*>(dbase + (size_t)k * E);
        const float4 a0 = p[0], a1 = p[1], a2 = p[2], a3 = p[3];
        float s = fdot4(a0, a0, 0.0f);
        s = fdot4(a1, a1, s);
        s = fdot4(a2, a2, s);
        s = fdot4(a3, a3, s);
        snd[k] = s;
    }
    __syncthreads();

    // ---- A fragments for this wave's two row-tiles
    const short8 a1_0 = sA1[w * 64 + lane];
    const short8 a2_0 = sA2[w * 64 + lane];
    const short8 a1_1 = sA1[(w + 4) * 64 + lane];
    const short8 a2_1 = sA2[(w + 4) * 64 + lane];

    float best[8], sec[8];
    int   bk[8];
#pragma unroll
    for (int i = 0; i < 8; ++i) { best[i] = FLT_MAX; sec[i] = FLT_MAX; bk[i] = 0; }

    float* ohr0 = oh + ((size_t)(b0 + w * 16) * C + c) * K;        // rt = w
    float* ohr1 = oh + ((size_t)(b0 + (w + 4) * 16) * C + c) * K;  // rt = w+4

    // ---- main ct-loop: 2 MFMAs x 2 row-tiles + interleaved one_hot fill
#pragma unroll 1
    for (int ct = 0; ct < 32; ++ct) {
        {   // zero-fill one of this wave's 32 rows per iter (2x float4/lane)
            float* base = (ct < 16)
                ? ohr0 + (size_t)ct * (C * K)
                : ohr1 + (size_t)(ct - 16) * (C * K);
            const float4 z4 = make_float4(0.f, 0.f, 0.f, 0.f);
            *reinterpret_cast<float4*>(base + lane * 4)       = z4;
            *reinterpret_cast<float4*>(base + 256 + lane * 4) = z4;
        }

        const short8 bf = sB[ct * 64 + lane];
        const float  ndl = snd[ct * 16 + (lane & 15)];
        floatx4 acc0 = {0.f, 0.f, 0.f, 0.f}, acc1 = {0.f, 0.f, 0.f, 0.f};
        acc0 = __builtin_amdgcn_mfma_f32_16x16x32_bf16(a1_0, bf, acc0, 0, 0, 0);
        acc0 = __builtin_amdgcn_mfma_f32_16x16x32_bf16(a2_0, bf, acc0, 0, 0, 0);
        acc1 = __builtin_amdgcn_mfma_f32_16x16x32_bf16(a1_1, bf, acc1, 0, 0, 0);
        acc1 = __builtin_amdgcn_mfma_f32_16x16x32_bf16(a2_1, bf, acc1, 0, 0, 0);

        const int code = ct * 16 + (lane & 15);
#pragma unroll
        for (int r = 0; r < 4; ++r) {
            const float d0 = fmaf(-2.0f, acc0[r], ndl);
            sec[r] = fminf(sec[r], fmaxf(best[r], d0));
            if (d0 < best[r]) { best[r] = d0; bk[r] = code; }
            const float d1 = fmaf(-2.0f, acc1[r], ndl);
            sec[4 + r] = fminf(sec[4 + r], fmaxf(best[4 + r], d1));
            if (d1 < best[4 + r]) { best[4 + r] = d1; bk[4 + r] = code; }
        }
    }

    // ---- reduce across the 16 lanes holding each C-row (cols of the tile).
    //      Ascending offsets 1,2,4,8: every chain feeding lane n=0 stays in
    //      its 16-lane group; shfl reads pre-step values, so cross-group
    //      garbage never reaches n=0.
#pragma unroll
    for (int off = 1; off < 16; off <<= 1) {
#pragma unroll
        for (int i = 0; i < 8; ++i) {
            const float ob  = __shfl_down(best[i], off);
            const int   obk = __shfl_down(bk[i],   off);
            const float os  = __shfl_down(sec[i],  off);
            sec[i] = fminf(fminf(sec[i], os), fmaxf(best[i], ob));
            if (ob < best[i] || (ob == best[i] && obk < bk[i])) {
                best[i] = ob; bk[i] = obk;
            }
        }
    }
    if ((lane & 15) == 0) {
        const int q = lane >> 4;
#pragma unroll
        for (int i = 0; i < 8; ++i) {
            const int rt  = (i < 4) ? w : (w + 4);
            const int row = rt * 16 + q * 4 + (i & 3);  // C-row = quad*4+reg
            rbest[row] = best[i];
            rsec[row]  = sec[i];
            rbk[row]   = bk[i];
        }
    }
    __syncthreads();   // also drains the one_hot fill stores (vmcnt(0))

    // ---- per-row epilogue: threads 0..127 own one row each
    if (tid < RPBLK) {
        const int b = b0 + tid;
        int bkr = rbk[tid];
        const float4* mp = reinterpret_cast<const float4*>(mu + (size_t)b * MUS + c * E);
        const float4 m0 = mp[0], m1 = mp[1], m2 = mp[2], m3 = mp[3];

        if (rsec[tid] - rbest[tid] < 3e-3f) {
            // verified fp32 decision function (rounds 4/5, absmax 0)
            float bb = FLT_MAX, ss = FLT_MAX;
            int   kk = 0;
            for (int k = 0; k < K; ++k) {
                const float4* p = reinterpret_cast<const float4*>(dbase + (size_t)k * E);
                const float4 a0 = p[0], a1 = p[1], a2 = p[2], a3 = p[3];
                float dot = fdot4(a0, m0, 0.0f);
                dot = fdot4(a1, m1, dot);
                dot = fdot4(a2, m2, dot);
                dot = fdot4(a3, m3, dot);
                const float dist = fmaf(-2.0f, dot, snd[k]);
                ss = fminf(ss, fmaxf(bb, dist));
                if (dist < bb) { bb = dist; kk = k; }
            }
            bkr = kk;
            if (ss - bb < 2.5e-4f) {
                // verified fp64 arbiter (round 4)
                double bdd = DBL_MAX;
                int    bkk = 0;
                for (int k = 0; k < K; ++k) {
                    const float4* p = reinterpret_cast<const float4*>(dbase + (size_t)k * E);
                    const float4 a0 = p[0], a1 = p[1], a2 = p[2], a3 = p[3];
                    double nd = dnrm4(a0, 0.0);
                    nd = dnrm4(a1, nd); nd = dnrm4(a2, nd); nd = dnrm4(a3, nd);
                    double dt = ddot4(a0, m0, 0.0);
                    dt = ddot4(a1, m1, dt); dt = ddot4(a2, m2, dt); dt = ddot4(a3, m3, dt);
                    const double dist = nd - 2.0 * dt;
                    if (dist < bdd) { bdd = dist; bkk = k; }
                }
                bkr = bkk;
            }
        }

        // zq = dict[bkr]; z = mu + (zq - mu) fp32 op-for-op (reference)
        const float4* qp = reinterpret_cast<const float4*>(dbase + (size_t)bkr * E);
        const float4 q0 = qp[0], q1 = qp[1], q2 = qp[2], q3 = qp[3];
        float4* zo  = reinterpret_cast<float4*>(z  + (size_t)b * MUS + c * E);
        float4* zqo = reinterpret_cast<float4*>(zq + (size_t)b * MUS + c * E);
        zqo[0] = q0; zqo[1] = q1; zqo[2] = q2; zqo[3] = q3;
        float4 r0, r1, r2, r3;
        r0.x = m0.x + (q0.x - m0.x); r0.y = m0.y + (q0.y - m0.y);
        r0.z = m0.z + (q0.z - m0.z); r0.w = m0.w + (q0.w - m0.w);
        r1.x = m1.x + (q1.x - m1.x); r1.y = m1.y + (q1.y - m1.y);
        r1.z = m1.z + (q1.z - m1.z); r1.w = m1.w + (q1.w - m1.w);
        r2.x = m2.x + (q2.x - m2.x); r2.y = m2.y + (q2.y - m2.y);
        r2.z = m2.z + (q2.z - m2.z); r2.w = m2.w + (q2.w - m2.w);
        r3.x = m3.x + (q3.x - m3.x); r3.y = m3.y + (q3.y - m3.y);
        r3.z = m3.z + (q3.z - m3.z); r3.w = m3.w + (q3.w - m3.w);
        zo[0] = r0; zo[1] = r1; zo[2] = r2; zo[3] = r3;

        // 1.0 scatter: fills were drained by the barrier above
        oh[((size_t)b * C + c) * K + bkr] = 1.0f;
    }
}

extern "C" void kernel_launch(void* const* d_in, const int* in_sizes, int n_in,
                              void* d_out, int out_size, void* d_ws, size_t ws_size,
                              hipStream_t stream)
{
    const float* mu   = (const float*)d_in[0];
    const float* dict = (const float*)d_in[1];

    float* z  = (float*)d_out;                 // (B, C*E)
    float* zq = z  + (size_t)B * C * E;        // (B, C*E)
    float* oh = zq + (size_t)B * C * E;        // (B, C, K)

    dim3 grid(C, B / RPBLK);                   // (512, 4) = 2048 blocks
    vq_kernel<<<grid, 256, 0, stream>>>(mu, dict, z, zq, oh);
}